// Round 2
// baseline (4145.927 us; speedup 1.0000x reference)
//
#include <hip/hip_runtime.h>
#include <cstdint>
#include <cstddef>

// Problem constants (fixed by the reference).
#define B_   2048
#define T_   100
#define U_   512
#define NG_  2048   // 4*U
#define C_   10

// NOTE (round-1 lesson): hipLaunchCooperativeKernel fails under the harness's
// graph capture (kernel silently never ran; output stayed zero). Use plain
// per-phase launches only.

typedef __attribute__((ext_vector_type(8))) short   short8;
typedef __attribute__((ext_vector_type(4))) float   floatx4;
typedef unsigned short ushort_t;

__device__ inline ushort_t f2bf(float f){
  unsigned u = __float_as_uint(f);
  unsigned r = (u + 0x7FFFu + ((u >> 16) & 1u)) >> 16;   // RNE
  return (ushort_t)r;
}
__device__ inline float bf2f(ushort_t b){ return __uint_as_float(((unsigned)b) << 16); }

__device__ inline float sigm(float x){ return 1.0f / (1.0f + __expf(-x)); }
__device__ inline float tanh_fast(float x){
  float a = fabsf(x);
  float e = __expf(-2.0f * a);          // no overflow: e in (0,1]
  float r = (1.0f - e) / (1.0f + e);
  return copysignf(r, x);
}

// Column permutation: permuted col p -> original gate-major col.
__device__ inline int orig_col(int p){
  int Tt  = p >> 7;
  int loc = p & 127;
  int half = loc >> 6;
  int loc2 = loc & 63;
  int gate = loc2 >> 4;
  int uu   = (half << 4) | (loc2 & 15);
  return gate * U_ + Tt * 32 + uu;
}

// h buffers live in MFMA-A-fragment layout:
//   idx(b,u) = (((b>>4)*64 + (u>>3))*16 + (b&15))*8 + (u&7)
// so a wave's A-fragment (16 rows x 8 k-elems, 4 k-chunks across qd) is a
// single contiguous, perfectly-coalesced 1KB global load.
__device__ inline size_t hidx(int b, int u){
  return (((size_t)(b >> 4) * 64 + (size_t)(u >> 3)) * 16 + (b & 15)) * 8 + (u & 7);
}

#define AS1(p) ((const __attribute__((address_space(1))) void*)(p))
#define AS3(p) ((__attribute__((address_space(3))) void*)(p))

// ---------------------------------------------------------------------------
// One-time weight repack: fp32 -> bf16, B^T (n-major) layout with
// gate-interleaved column permutation. Also permuted biases (fp32) and W0 row.
// ---------------------------------------------------------------------------
__global__ void convert_weights(
    const float* __restrict__ W0, const float* __restrict__ U0, const float* __restrict__ b0,
    const float* __restrict__ W1, const float* __restrict__ U1, const float* __restrict__ b1,
    const float* __restrict__ W2, const float* __restrict__ U2, const float* __restrict__ b2,
    ushort_t* __restrict__ Bt0, ushort_t* __restrict__ Bt1, ushort_t* __restrict__ Bt2,
    float* __restrict__ W0p, float* __restrict__ biasp)
{
  const int N0 = NG_ * 512;     // Bt0 elements
  const int N1 = NG_ * 1024;    // Bt1/Bt2 elements
  const int total = N0 + 2 * N1 + NG_ + 3 * NG_;
  int idx = blockIdx.x * 256 + threadIdx.x;
  if (idx >= total) return;

  if (idx < N0){
    int p = idx >> 9, k = idx & 511;
    Bt0[idx] = f2bf(U0[(size_t)k * NG_ + orig_col(p)]);
  } else if (idx < N0 + N1){
    int j = idx - N0; int p = j >> 10, k = j & 1023;
    int oc = orig_col(p);
    float v = (k < 512) ? W1[(size_t)k * NG_ + oc] : U1[(size_t)(k - 512) * NG_ + oc];
    Bt1[j] = f2bf(v);
  } else if (idx < N0 + 2 * N1){
    int j = idx - N0 - N1; int p = j >> 10, k = j & 1023;
    int oc = orig_col(p);
    float v = (k < 512) ? W2[(size_t)k * NG_ + oc] : U2[(size_t)(k - 512) * NG_ + oc];
    Bt2[j] = f2bf(v);
  } else if (idx < N0 + 2 * N1 + NG_){
    int p = idx - N0 - 2 * N1;
    W0p[p] = W0[orig_col(p)];
  } else {
    int j = idx - N0 - 2 * N1 - NG_;
    int l = j >> 11, p = j & 2047;
    const float* bs = (l == 0) ? b0 : (l == 1) ? b1 : b2;
    biasp[j] = bs[orig_col(p)];
  }
}

// ---------------------------------------------------------------------------
// One fused GEMM (bf16 MFMA) + LSTM-cell task for a (layer, timestep),
// 128x128 tile at (mt, nt).
//  - A (activations) read DIRECTLY from global in fragment layout (no LDS,
//    no inter-wave sharing needed; h is 2MB -> L2-resident).
//  - B (weights) staged via global_load_lds with the conflict-free slot
//    rotation, double-buffered: ONE barrier per BK=64 K-iter.
//  - A-frag loads are issued before the stage loads so the MFMA wait for af
//    leaves the next tile's stage loads in flight.
// ---------------------------------------------------------------------------
template<int LAYER>
__device__ __forceinline__ void do_task(
    const ushort_t* __restrict__ A0,   // phase-0 A (h_below / h_prev for L0), frag layout
    const ushort_t* __restrict__ A1,   // phase-1 A (h_prev), LAYER>0, frag layout
    const ushort_t* __restrict__ Bt,   // (2048 x K) bf16, n-major permuted
    const float* __restrict__ biasp,   // permuted bias for this layer (2048)
    const float* __restrict__ W0p,     // permuted W0 row (L0 only)
    const float* __restrict__ x,       // (B,T) fp32 (L0 only)
    const int* __restrict__ mask,      // (B,T) int32
    float* __restrict__ cbuf,          // (B,U) fp32 linear, in/out
    const ushort_t* __restrict__ hprev,// this layer's previous h (mask carry), frag layout
    ushort_t* __restrict__ hout,       // h out, frag layout
    int t, int mt, int nt,
    ushort_t* tB)                      // [2][128*64] double-buffered
{
  constexpr int NPHASE = (LAYER == 0) ? 1 : 2;
  constexpr bool IS_L0 = (LAYER == 0);
  constexpr int K  = NPHASE * 512;
  constexpr int NK = NPHASE * 8;      // BK=64 iterations

  const int tid  = threadIdx.x;
  const int wv   = tid >> 6;
  const int lane = tid & 63;
  const int qd   = lane >> 4;     // quad 0..3
  const int l16  = lane & 15;
  const int wave_m = wv >> 1;     // 0..1
  const int wave_n = wv & 1;      // 0..1
  const int m0 = mt * 128, n0 = nt * 128;

  // B staging identity: 1024 16B-chunks of a 128x64 tile, 4 per thread;
  // slot (r,j) holds source chunk (j+r)&7 (bank-conflict-killing rotation).
  int srow[4], scol[4];
  #pragma unroll
  for (int cc = 0; cc < 4; ++cc){
    int i = cc * 256 + tid;
    srow[cc] = i >> 3;
    scol[cc] = ((i & 7) + (i >> 3)) & 7;
  }

  // B LDS read offsets (elements): row R, chunk q = ks*4+qd at slot (q-R)&7.
  int boff[2][4];
  #pragma unroll
  for (int ks = 0; ks < 2; ++ks){
    #pragma unroll
    for (int w = 0; w < 4; ++w){
      int Rb = wave_n * 64 + w * 16 + l16;
      int q  = ks * 4 + qd;
      boff[ks][w] = Rb * 64 + ((q - Rb) & 7) * 8;
    }
  }

  // A direct-load per-lane bases (elements within a 512-col frag buffer):
  // addr = abase[wm] + k0*16 + ks*512
  size_t abase[4];
  #pragma unroll
  for (int wm = 0; wm < 4; ++wm)
    abase[wm] = ((size_t)((m0 >> 4) + wave_m * 4 + wm)) * 8192
              + (size_t)qd * 128 + (size_t)l16 * 8;

  floatx4 acc[4][4];
  #pragma unroll
  for (int i = 0; i < 4; ++i)
    #pragma unroll
    for (int j = 0; j < 4; ++j) acc[i][j] = (floatx4){0.f, 0.f, 0.f, 0.f};

  auto stageB = [&](int kk, int buf){
    const int phh = kk >> 3;
    const int kk0 = (kk & 7) << 6;
    ushort_t* dst = tB + buf * 8192;
    #pragma unroll
    for (int cc = 0; cc < 4; ++cc){
      const int ibase = cc * 256 + wv * 64;   // wave-uniform LDS base (HW adds lane*16B)
      const ushort_t* gb = Bt + (size_t)(n0 + srow[cc]) * K + phh * 512 + kk0 + scol[cc] * 8;
      __builtin_amdgcn_global_load_lds(AS1(gb), AS3(&dst[ibase * 8]), 16, 0, 0);
    }
  };

  stageB(0, 0);
  __syncthreads();

  int cur = 0;
  for (int kk = 0; kk < NK; ++kk){
    const int k0 = (kk & 7) << 6;
    const ushort_t* A = (NPHASE == 2 && kk >= 8) ? A1 : A0;

    // A-fragments: 8 coalesced 16B loads straight to VGPR (issued FIRST).
    short8 af[2][4];
    #pragma unroll
    for (int ks = 0; ks < 2; ++ks)
      #pragma unroll
      for (int wm = 0; wm < 4; ++wm)
        af[ks][wm] = *(const short8*)&A[abase[wm] + (size_t)(k0 * 16 + ks * 512)];

    // Prefetch next B tile into the other buffer (in flight across the MFMAs).
    if (kk + 1 < NK) stageB(kk + 1, cur ^ 1);

    const ushort_t* tb = tB + cur * 8192;
    #pragma unroll
    for (int ks = 0; ks < 2; ++ks){
      short8 bfr[4];
      #pragma unroll
      for (int wn = 0; wn < 4; ++wn)
        bfr[wn] = *(const short8*)&tb[boff[ks][wn]];
      #pragma unroll
      for (int wm = 0; wm < 4; ++wm)
        #pragma unroll
        for (int wn = 0; wn < 4; ++wn)
          acc[wm][wn] = __builtin_amdgcn_mfma_f32_16x16x32_bf16(af[ks][wm], bfr[wn], acc[wm][wn], 0, 0, 0);
    }
    __syncthreads();   // drains stage(kk+1); next iter reads it & may overwrite old buf
    cur ^= 1;
  }

  // ---- epilogue: LSTM cell, fully in-register per lane ----
  const int u  = nt * 32 + wave_n * 16 + l16;
  const int pb = nt * 128 + wave_n * 64 + l16;
  const float bi = biasp[pb], bf_ = biasp[pb + 16], bg = biasp[pb + 32], bo = biasp[pb + 48];
  float wi = 0.f, wf = 0.f, wg = 0.f, wo = 0.f;
  if (IS_L0){ wi = W0p[pb]; wf = W0p[pb + 16]; wg = W0p[pb + 32]; wo = W0p[pb + 48]; }

  #pragma unroll
  for (int wm = 0; wm < 4; ++wm){
    #pragma unroll
    for (int reg = 0; reg < 4; ++reg){
      int b = m0 + wave_m * 64 + wm * 16 + qd * 4 + reg;
      float zi = acc[wm][0][reg] + bi;
      float zf = acc[wm][1][reg] + bf_;
      float zg = acc[wm][2][reg] + bg;
      float zo = acc[wm][3][reg] + bo;
      if (IS_L0){
        float xv = x[(size_t)b * T_ + t];
        zi += xv * wi; zf += xv * wf; zg += xv * wg; zo += xv * wo;
      }
      int mk = mask[(size_t)b * T_ + t];
      size_t su = (size_t)b * U_ + u;       // c stays linear
      size_t sf = hidx(b, u);               // h in fragment layout
      float c_old = cbuf[su];
      float i_ = sigm(zi), f_ = sigm(zf), g_ = tanh_fast(zg), o_ = sigm(zo);
      float c_new = f_ * c_old + i_ * g_;
      float h_new = o_ * tanh_fast(c_new);
      ushort_t hb = mk ? f2bf(h_new) : hprev[sf];
      cbuf[su] = mk ? c_new : c_old;
      hout[sf] = hb;
    }
  }
}

// ---------------------------------------------------------------------------
// One wavefront phase: L0(t=s), L1(t=s-1), L2(t=s-2) are independent ->
// 768 blocks (3 tasks x 256 tiles) = 3 blocks/CU.
// ---------------------------------------------------------------------------
__global__ __launch_bounds__(256, 3) void lstm_phase(
    const ushort_t* __restrict__ Bt0, const ushort_t* __restrict__ Bt1,
    const ushort_t* __restrict__ Bt2, const float* __restrict__ biasp,
    const float* __restrict__ W0p, const float* __restrict__ x,
    const int* __restrict__ mask,
    ushort_t* h00, ushort_t* h01, ushort_t* h10, ushort_t* h11,
    ushort_t* h20, ushort_t* h21,
    float* c0, float* c1, float* c2,
    int s)
{
  __shared__ __align__(16) ushort_t tB[2 * 128 * 64];   // 32 KB double buffer

  const int lin  = blockIdx.x;
  const int task = lin >> 8;        // 0..2
  const int tile = lin & 255;       // 0..255
  const int mt = tile >> 4, nt = tile & 15;

  ushort_t* h0[2] = {h00, h01};
  ushort_t* h1[2] = {h10, h11};
  ushort_t* h2[2] = {h20, h21};

  if (task == 0){
    if (s >= 100) return;
    int t = s, p = t & 1;
    do_task<0>(h0[p], nullptr, Bt0, biasp, W0p, x, mask,
               c0, h0[p], h0[p ^ 1], t, mt, nt, tB);
  } else if (task == 1){
    if (s < 1 || s > 100) return;
    int t = s - 1, p = t & 1;
    do_task<1>(h0[p ^ 1], h1[p], Bt1, biasp + NG_, nullptr, x, mask,
               c1, h1[p], h1[p ^ 1], t, mt, nt, tB);
  } else {
    if (s < 2) return;
    int t = s - 2, p = t & 1;
    do_task<2>(h1[p ^ 1], h2[p], Bt2, biasp + 2 * NG_, nullptr, x, mask,
               c2, h2[p], h2[p ^ 1], t, mt, nt, tB);
  }
}

// ---------------------------------------------------------------------------
// Head: logits = h2 @ Wd + bd, softmax. One wave per batch row.
// h2 is in fragment layout: chunk C = lane holds u = lane*8 .. lane*8+7.
// ---------------------------------------------------------------------------
__global__ __launch_bounds__(256) void head_softmax(
    const ushort_t* __restrict__ h2, const float* __restrict__ Wd,
    const float* __restrict__ bd, float* __restrict__ out)
{
  int wv = threadIdx.x >> 6, lane = threadIdx.x & 63;
  int row = blockIdx.x * 4 + wv;
  const ushort_t* hr = h2 + (((size_t)(row >> 4) * 64 + lane) * 16 + (row & 15)) * 8;

  float acc[C_];
  #pragma unroll
  for (int c = 0; c < C_; ++c) acc[c] = 0.f;

  short8 hv = *(const short8*)hr;
  #pragma unroll
  for (int j = 0; j < 8; ++j){
    float hf = bf2f((ushort_t)hv[j]);
    int k = lane * 8 + j;
    #pragma unroll
    for (int c = 0; c < C_; ++c) acc[c] += hf * Wd[k * C_ + c];
  }
  #pragma unroll
  for (int c = 0; c < C_; ++c){
    float v = acc[c];
    #pragma unroll
    for (int off = 32; off > 0; off >>= 1) v += __shfl_xor(v, off);
    acc[c] = v + bd[c];
  }
  float mx = acc[0];
  #pragma unroll
  for (int c = 1; c < C_; ++c) mx = fmaxf(mx, acc[c]);
  float e[C_]; float s = 0.f;
  #pragma unroll
  for (int c = 0; c < C_; ++c){ e[c] = __expf(acc[c] - mx); s += e[c]; }
  float inv = 1.0f / s;
  if (lane == 0){
    #pragma unroll
    for (int c = 0; c < C_; ++c) out[(size_t)row * C_ + c] = e[c] * inv;
  }
}

// ---------------------------------------------------------------------------
extern "C" void kernel_launch(void* const* d_in, const int* in_sizes, int n_in,
                              void* d_out, int out_size, void* d_ws, size_t ws_size,
                              hipStream_t stream)
{
  const float* x  = (const float*)d_in[0];
  const int*  mask= (const int*)  d_in[1];
  const float* W0 = (const float*)d_in[2];
  const float* U0 = (const float*)d_in[3];
  const float* b0 = (const float*)d_in[4];
  const float* W1 = (const float*)d_in[5];
  const float* U1 = (const float*)d_in[6];
  const float* b1 = (const float*)d_in[7];
  const float* W2 = (const float*)d_in[8];
  const float* U2 = (const float*)d_in[9];
  const float* b2 = (const float*)d_in[10];
  const float* Wd = (const float*)d_in[11];
  const float* bd = (const float*)d_in[12];
  float* out = (float*)d_out;

  char* ws = (char*)d_ws;
  size_t off = 0;
  auto alloc = [&](size_t sz) -> char* {
    char* p = ws + off; off = (off + sz + 255) & ~(size_t)255; return p;
  };
  ushort_t* Bt0  = (ushort_t*)alloc((size_t)NG_ * 512 * 2);
  ushort_t* Bt1  = (ushort_t*)alloc((size_t)NG_ * 1024 * 2);
  ushort_t* Bt2  = (ushort_t*)alloc((size_t)NG_ * 1024 * 2);
  float*    W0p  = (float*)alloc((size_t)NG_ * 4);
  float*    biasp= (float*)alloc((size_t)3 * NG_ * 4);

  // State: h[3][2] (bf16, fragment layout) + c[3] (fp32 linear).
  const size_t hsz = (size_t)B_ * U_ * 2;
  const size_t csz = (size_t)B_ * U_ * 4;
  char* state = alloc(6 * hsz + 3 * csz);
  ushort_t* hb[3][2]; float* cb[3];
  {
    char* pp = state;
    for (int l = 0; l < 3; ++l)
      for (int par = 0; par < 2; ++par){ hb[l][par] = (ushort_t*)pp; pp += hsz; }
    for (int l = 0; l < 3; ++l){ cb[l] = (float*)pp; pp += csz; }
  }

  hipMemsetAsync(state, 0, 6 * hsz + 3 * csz, stream);

  const int total = NG_ * 512 + 2 * NG_ * 1024 + NG_ + 3 * NG_;
  convert_weights<<<(total + 255) / 256, 256, 0, stream>>>(
      W0, U0, b0, W1, U1, b1, W2, U2, b2, Bt0, Bt1, Bt2, W0p, biasp);

  for (int s = 0; s < 102; ++s){
    lstm_phase<<<768, 256, 0, stream>>>(
        Bt0, Bt1, Bt2, biasp, W0p, x, mask,
        hb[0][0], hb[0][1], hb[1][0], hb[1][1], hb[2][0], hb[2][1],
        cb[0], cb[1], cb[2], s);
  }

  // T=100: layer-2 final h (t=99) lands in parity-0 buffer.
  head_softmax<<<B_ / 4, 256, 0, stream>>>(hb[2][0], Wd, bd, out);
}

// Round 3
// 4045.770 us; speedup vs baseline: 1.0248x; 1.0248x over previous
//
#include <hip/hip_runtime.h>
#include <cstdint>
#include <cstddef>

// Problem constants (fixed by the reference).
#define B_   2048
#define T_   100
#define U_   512
#define NG_  2048   // 4*U
#define C_   10

// NOTE (round-1 lesson): hipLaunchCooperativeKernel fails under the harness's
// graph capture (kernel silently never ran; output stayed zero). Plain
// per-phase launches only.
// NOTE (round-2 lesson): A-direct-from-global regressed (44.5us/dispatch,
// MfmaUtil 17%) — h working set misses L2 (10MB/XCD > 4MB) so per-iter L3
// latency landed on the MFMA critical path. This round: LDS staging for both
// operands + counted-vmcnt pipeline (T3/T4), depth-2 lookahead, triple buffer.

typedef __attribute__((ext_vector_type(8))) short   short8;
typedef __attribute__((ext_vector_type(4))) float   floatx4;
typedef unsigned short ushort_t;

__device__ inline ushort_t f2bf(float f){
  unsigned u = __float_as_uint(f);
  unsigned r = (u + 0x7FFFu + ((u >> 16) & 1u)) >> 16;   // RNE
  return (ushort_t)r;
}
__device__ inline float bf2f(ushort_t b){ return __uint_as_float(((unsigned)b) << 16); }

__device__ inline float sigm(float x){ return 1.0f / (1.0f + __expf(-x)); }
__device__ inline float tanh_fast(float x){
  float a = fabsf(x);
  float e = __expf(-2.0f * a);          // no overflow: e in (0,1]
  float r = (1.0f - e) / (1.0f + e);
  return copysignf(r, x);
}

// Column permutation: permuted col p -> original gate-major col.
__device__ inline int orig_col(int p){
  int Tt  = p >> 7;
  int loc = p & 127;
  int half = loc >> 6;
  int loc2 = loc & 63;
  int gate = loc2 >> 4;
  int uu   = (half << 4) | (loc2 & 15);
  return gate * U_ + Tt * 32 + uu;
}

#define AS1(p) ((const __attribute__((address_space(1))) void*)(p))
#define AS3(p) ((__attribute__((address_space(3))) void*)(p))

// ---------------------------------------------------------------------------
// One-time weight repack: fp32 -> bf16, B^T (n-major) layout with
// gate-interleaved column permutation. Also permuted biases (fp32) and W0 row.
// ---------------------------------------------------------------------------
__global__ void convert_weights(
    const float* __restrict__ W0, const float* __restrict__ U0, const float* __restrict__ b0,
    const float* __restrict__ W1, const float* __restrict__ U1, const float* __restrict__ b1,
    const float* __restrict__ W2, const float* __restrict__ U2, const float* __restrict__ b2,
    ushort_t* __restrict__ Bt0, ushort_t* __restrict__ Bt1, ushort_t* __restrict__ Bt2,
    float* __restrict__ W0p, float* __restrict__ biasp)
{
  const int N0 = NG_ * 512;     // Bt0 elements
  const int N1 = NG_ * 1024;    // Bt1/Bt2 elements
  const int total = N0 + 2 * N1 + NG_ + 3 * NG_;
  int idx = blockIdx.x * 256 + threadIdx.x;
  if (idx >= total) return;

  if (idx < N0){
    int p = idx >> 9, k = idx & 511;
    Bt0[idx] = f2bf(U0[(size_t)k * NG_ + orig_col(p)]);
  } else if (idx < N0 + N1){
    int j = idx - N0; int p = j >> 10, k = j & 1023;
    int oc = orig_col(p);
    float v = (k < 512) ? W1[(size_t)k * NG_ + oc] : U1[(size_t)(k - 512) * NG_ + oc];
    Bt1[j] = f2bf(v);
  } else if (idx < N0 + 2 * N1){
    int j = idx - N0 - N1; int p = j >> 10, k = j & 1023;
    int oc = orig_col(p);
    float v = (k < 512) ? W2[(size_t)k * NG_ + oc] : U2[(size_t)(k - 512) * NG_ + oc];
    Bt2[j] = f2bf(v);
  } else if (idx < N0 + 2 * N1 + NG_){
    int p = idx - N0 - 2 * N1;
    W0p[p] = W0[orig_col(p)];
  } else {
    int j = idx - N0 - 2 * N1 - NG_;
    int l = j >> 11, p = j & 2047;
    const float* bs = (l == 0) ? b0 : (l == 1) ? b1 : b2;
    biasp[j] = bs[orig_col(p)];
  }
}

// ---------------------------------------------------------------------------
// One fused GEMM (bf16 MFMA) + LSTM-cell task for a (layer, timestep),
// 128x128 tile at (mt, nt). BK=32 K-steps; A and B both staged via
// global_load_lds(16B) into a TRIPLE-buffered LDS set (8KB each per buf).
// Pipeline: iter kk stages kk+2, computes kk, then waits vmcnt(4) (own
// stage loads for kk+1 only; kk+2's 4 stay in flight), lgkmcnt(0), raw
// s_barrier. Never drains the prefetch (T3/T4 counted-vmcnt recipe).
//
// Slot rotation (bank-conflict-free, 4 chunks/row): LDS slot j of row r
// holds source 16B-chunk (j + (r>>1)) & 3; reader of chunk q at row R uses
// slot (q - (R>>1)) & 3 -> 16-lane ds_read_b128 groups land 2-way (free).
// ---------------------------------------------------------------------------
template<int LAYER>
__device__ __forceinline__ void do_task(
    const ushort_t* __restrict__ A0,   // phase-0 A rows (h_below / h_prev for L0), linear (B,U)
    const ushort_t* __restrict__ A1,   // phase-1 A rows (h_prev), LAYER>0
    const ushort_t* __restrict__ Bt,   // (2048 x K) bf16, n-major permuted
    const float* __restrict__ biasp,   // permuted bias for this layer (2048)
    const float* __restrict__ W0p,     // permuted W0 row (L0 only)
    const float* __restrict__ x,       // (B,T) fp32 (L0 only)
    const int* __restrict__ mask,      // (B,T) int32
    float* __restrict__ cbuf,          // (B,U) fp32, in/out
    const ushort_t* __restrict__ hprev,// this layer's previous h (mask carry)
    ushort_t* __restrict__ hout,       // (B,U) bf16 out
    int t, int mt, int nt,
    ushort_t* tA, ushort_t* tB)        // [3][128*32] each (triple-buffered)
{
  constexpr int NPHASE = (LAYER == 0) ? 1 : 2;
  constexpr bool IS_L0 = (LAYER == 0);
  constexpr int K  = NPHASE * 512;
  constexpr int NK = NPHASE * 16;     // BK=32 iterations

  const int tid  = threadIdx.x;
  const int wv   = tid >> 6;
  const int lane = tid & 63;
  const int qd   = lane >> 4;     // quad 0..3 (k-chunk)
  const int l16  = lane & 15;
  const int wave_m = wv >> 1;     // 0..1
  const int wave_n = wv & 1;      // 0..1
  const int m0 = mt * 128, n0 = nt * 128;

  // Staging identity: 512 chunks per 128x32 tile, 2 per thread per matrix.
  // chunk i: row r = i>>2, slot j = i&3, source chunk (j + (r>>1)) & 3.
  int srow[2], scol[2];
  #pragma unroll
  for (int cc = 0; cc < 2; ++cc){
    int i = cc * 256 + tid;
    srow[cc] = i >> 2;
    scol[cc] = ((i & 3) + ((i >> 2) >> 1)) & 3;
  }

  // LDS read offsets (elements): row R, chunk q=qd at slot (q - (R>>1)) & 3.
  int aoff[4], boff[4];
  #pragma unroll
  for (int w = 0; w < 4; ++w){
    int Ra = wave_m * 64 + w * 16 + l16;
    int Rb = wave_n * 64 + w * 16 + l16;
    aoff[w] = Ra * 32 + ((qd - (Ra >> 1)) & 3) * 8;
    boff[w] = Rb * 32 + ((qd - (Rb >> 1)) & 3) * 8;
  }

  floatx4 acc[4][4];
  #pragma unroll
  for (int i = 0; i < 4; ++i)
    #pragma unroll
    for (int j = 0; j < 4; ++j) acc[i][j] = (floatx4){0.f, 0.f, 0.f, 0.f};

  // Stage iter kk into buffer b: 2 A-chunks + 2 B-chunks per thread = 4 loads.
  auto stage = [&](int kk, int b){
    const ushort_t* A = (NPHASE == 2 && kk >= 16) ? A1 : A0;
    const int kk0 = (kk & 15) << 5;      // k-offset within the 512-col source
    ushort_t* dA = tA + b * 4096;
    ushort_t* dB = tB + b * 4096;
    #pragma unroll
    for (int cc = 0; cc < 2; ++cc){
      const int ibase = cc * 256 + wv * 64;   // wave-uniform chunk base (HW adds lane*16B)
      const ushort_t* ga = A + (size_t)(m0 + srow[cc]) * U_ + kk0 + scol[cc] * 8;
      __builtin_amdgcn_global_load_lds(AS1(ga), AS3(&dA[ibase * 8]), 16, 0, 0);
      const ushort_t* gb = Bt + (size_t)(n0 + srow[cc]) * K + kk * 32 + scol[cc] * 8;
      __builtin_amdgcn_global_load_lds(AS1(gb), AS3(&dB[ibase * 8]), 16, 0, 0);
    }
  };

  // Prologue: stage iters 0 and 1; wait for iter 0 only (vmcnt 4 = iter 1's
  // loads still in flight), then barrier.
  stage(0, 0);
  stage(1, 1);
  asm volatile("s_waitcnt vmcnt(4)" ::: "memory");
  __builtin_amdgcn_s_barrier();
  __builtin_amdgcn_sched_barrier(0);

  #pragma unroll
  for (int kk = 0; kk < NK; ++kk){
    const int buf = kk % 3;

    // Prefetch depth 2: stage kk+2 into the third buffer.
    if (kk + 2 < NK) stage(kk + 2, (kk + 2) % 3);

    const ushort_t* ta = tA + buf * 4096;
    const ushort_t* tb = tB + buf * 4096;
    short8 af[4], bfr[4];
    #pragma unroll
    for (int w = 0; w < 4; ++w) af[w]  = *(const short8*)&ta[aoff[w]];
    #pragma unroll
    for (int w = 0; w < 4; ++w) bfr[w] = *(const short8*)&tb[boff[w]];
    #pragma unroll
    for (int wm = 0; wm < 4; ++wm)
      #pragma unroll
      for (int wn = 0; wn < 4; ++wn)
        acc[wm][wn] = __builtin_amdgcn_mfma_f32_16x16x32_bf16(af[wm], bfr[wn], acc[wm][wn], 0, 0, 0);

    // kk+1's stage loads (issued last iter, older than kk+2's 4) must be
    // done; kk+2's 4 stay in flight. lgkmcnt(0): my ds_reads retired so the
    // barrier certifies buf[kk] free for overwrite next iter.
    if (kk + 2 < NK) asm volatile("s_waitcnt vmcnt(4) lgkmcnt(0)" ::: "memory");
    else             asm volatile("s_waitcnt vmcnt(0) lgkmcnt(0)" ::: "memory");
    __builtin_amdgcn_s_barrier();
    __builtin_amdgcn_sched_barrier(0);
  }

  // ---- epilogue: LSTM cell, fully in-register per lane ----
  const int u  = nt * 32 + wave_n * 16 + l16;
  const int pb = nt * 128 + wave_n * 64 + l16;
  const float bi = biasp[pb], bf_ = biasp[pb + 16], bg = biasp[pb + 32], bo = biasp[pb + 48];
  float wi = 0.f, wf = 0.f, wg = 0.f, wo = 0.f;
  if (IS_L0){ wi = W0p[pb]; wf = W0p[pb + 16]; wg = W0p[pb + 32]; wo = W0p[pb + 48]; }

  #pragma unroll
  for (int wm = 0; wm < 4; ++wm){
    #pragma unroll
    for (int reg = 0; reg < 4; ++reg){
      int b = m0 + wave_m * 64 + wm * 16 + qd * 4 + reg;
      float zi = acc[wm][0][reg] + bi;
      float zf = acc[wm][1][reg] + bf_;
      float zg = acc[wm][2][reg] + bg;
      float zo = acc[wm][3][reg] + bo;
      if (IS_L0){
        float xv = x[(size_t)b * T_ + t];
        zi += xv * wi; zf += xv * wf; zg += xv * wg; zo += xv * wo;
      }
      int mk = mask[(size_t)b * T_ + t];
      size_t su = (size_t)b * U_ + u;
      float c_old = cbuf[su];
      float i_ = sigm(zi), f_ = sigm(zf), g_ = tanh_fast(zg), o_ = sigm(zo);
      float c_new = f_ * c_old + i_ * g_;
      float h_new = o_ * tanh_fast(c_new);
      ushort_t hb = mk ? f2bf(h_new) : hprev[su];
      cbuf[su] = mk ? c_new : c_old;
      hout[su] = hb;
    }
  }
}

// ---------------------------------------------------------------------------
// One wavefront phase: L0(t=s), L1(t=s-1), L2(t=s-2) are independent ->
// 768 blocks (3 tasks x 256 tiles) = 3 blocks/CU (48KB LDS each, 144KB/CU).
// XCD = nt mod 8 under round-robin -> each XCD's weight slice (1.25MB) is
// L2-resident across phases.
// ---------------------------------------------------------------------------
__global__ __launch_bounds__(256, 3) void lstm_phase(
    const ushort_t* __restrict__ Bt0, const ushort_t* __restrict__ Bt1,
    const ushort_t* __restrict__ Bt2, const float* __restrict__ biasp,
    const float* __restrict__ W0p, const float* __restrict__ x,
    const int* __restrict__ mask,
    ushort_t* h00, ushort_t* h01, ushort_t* h10, ushort_t* h11,
    ushort_t* h20, ushort_t* h21,
    float* c0, float* c1, float* c2,
    int s)
{
  __shared__ __align__(16) ushort_t tA[3 * 128 * 32];   // 24 KB
  __shared__ __align__(16) ushort_t tB[3 * 128 * 32];   // 24 KB

  const int lin  = blockIdx.x;
  const int task = lin >> 8;        // 0..2
  const int tile = lin & 255;       // 0..255
  const int mt = tile >> 4, nt = tile & 15;

  ushort_t* h0[2] = {h00, h01};
  ushort_t* h1[2] = {h10, h11};
  ushort_t* h2[2] = {h20, h21};

  if (task == 0){
    if (s >= 100) return;
    int t = s, p = t & 1;
    do_task<0>(h0[p], nullptr, Bt0, biasp, W0p, x, mask,
               c0, h0[p], h0[p ^ 1], t, mt, nt, tA, tB);
  } else if (task == 1){
    if (s < 1 || s > 100) return;
    int t = s - 1, p = t & 1;
    do_task<1>(h0[p ^ 1], h1[p], Bt1, biasp + NG_, nullptr, x, mask,
               c1, h1[p], h1[p ^ 1], t, mt, nt, tA, tB);
  } else {
    if (s < 2) return;
    int t = s - 2, p = t & 1;
    do_task<2>(h1[p ^ 1], h2[p], Bt2, biasp + 2 * NG_, nullptr, x, mask,
               c2, h2[p], h2[p ^ 1], t, mt, nt, tA, tB);
  }
}

// ---------------------------------------------------------------------------
// Head: logits = h2 @ Wd + bd, softmax. One wave per batch row.
// ---------------------------------------------------------------------------
__global__ __launch_bounds__(256) void head_softmax(
    const ushort_t* __restrict__ h2, const float* __restrict__ Wd,
    const float* __restrict__ bd, float* __restrict__ out)
{
  int wv = threadIdx.x >> 6, lane = threadIdx.x & 63;
  int row = blockIdx.x * 4 + wv;
  const ushort_t* hr = h2 + (size_t)row * U_;

  float acc[C_];
  #pragma unroll
  for (int c = 0; c < C_; ++c) acc[c] = 0.f;

  short8 hv = *(const short8*)&hr[lane * 8];
  #pragma unroll
  for (int j = 0; j < 8; ++j){
    float hf = bf2f((ushort_t)hv[j]);
    int k = lane * 8 + j;
    #pragma unroll
    for (int c = 0; c < C_; ++c) acc[c] += hf * Wd[k * C_ + c];
  }
  #pragma unroll
  for (int c = 0; c < C_; ++c){
    float v = acc[c];
    #pragma unroll
    for (int off = 32; off > 0; off >>= 1) v += __shfl_xor(v, off);
    acc[c] = v + bd[c];
  }
  float mx = acc[0];
  #pragma unroll
  for (int c = 1; c < C_; ++c) mx = fmaxf(mx, acc[c]);
  float e[C_]; float s = 0.f;
  #pragma unroll
  for (int c = 0; c < C_; ++c){ e[c] = __expf(acc[c] - mx); s += e[c]; }
  float inv = 1.0f / s;
  if (lane == 0){
    #pragma unroll
    for (int c = 0; c < C_; ++c) out[(size_t)row * C_ + c] = e[c] * inv;
  }
}

// ---------------------------------------------------------------------------
extern "C" void kernel_launch(void* const* d_in, const int* in_sizes, int n_in,
                              void* d_out, int out_size, void* d_ws, size_t ws_size,
                              hipStream_t stream)
{
  const float* x  = (const float*)d_in[0];
  const int*  mask= (const int*)  d_in[1];
  const float* W0 = (const float*)d_in[2];
  const float* U0 = (const float*)d_in[3];
  const float* b0 = (const float*)d_in[4];
  const float* W1 = (const float*)d_in[5];
  const float* U1 = (const float*)d_in[6];
  const float* b1 = (const float*)d_in[7];
  const float* W2 = (const float*)d_in[8];
  const float* U2 = (const float*)d_in[9];
  const float* b2 = (const float*)d_in[10];
  const float* Wd = (const float*)d_in[11];
  const float* bd = (const float*)d_in[12];
  float* out = (float*)d_out;

  char* ws = (char*)d_ws;
  size_t off = 0;
  auto alloc = [&](size_t sz) -> char* {
    char* p = ws + off; off = (off + sz + 255) & ~(size_t)255; return p;
  };
  ushort_t* Bt0  = (ushort_t*)alloc((size_t)NG_ * 512 * 2);
  ushort_t* Bt1  = (ushort_t*)alloc((size_t)NG_ * 1024 * 2);
  ushort_t* Bt2  = (ushort_t*)alloc((size_t)NG_ * 1024 * 2);
  float*    W0p  = (float*)alloc((size_t)NG_ * 4);
  float*    biasp= (float*)alloc((size_t)3 * NG_ * 4);

  // State: h[3][2] (bf16) + c[3] (fp32), one contiguous memset region.
  const size_t hsz = (size_t)B_ * U_ * 2;
  const size_t csz = (size_t)B_ * U_ * 4;
  char* state = alloc(6 * hsz + 3 * csz);
  ushort_t* hb[3][2]; float* cb[3];
  {
    char* pp = state;
    for (int l = 0; l < 3; ++l)
      for (int par = 0; par < 2; ++par){ hb[l][par] = (ushort_t*)pp; pp += hsz; }
    for (int l = 0; l < 3; ++l){ cb[l] = (float*)pp; pp += csz; }
  }

  hipMemsetAsync(state, 0, 6 * hsz + 3 * csz, stream);

  const int total = NG_ * 512 + 2 * NG_ * 1024 + NG_ + 3 * NG_;
  convert_weights<<<(total + 255) / 256, 256, 0, stream>>>(
      W0, U0, b0, W1, U1, b1, W2, U2, b2, Bt0, Bt1, Bt2, W0p, biasp);

  for (int s = 0; s < 102; ++s){
    lstm_phase<<<768, 256, 0, stream>>>(
        Bt0, Bt1, Bt2, biasp, W0p, x, mask,
        hb[0][0], hb[0][1], hb[1][0], hb[1][1], hb[2][0], hb[2][1],
        cb[0], cb[1], cb[2], s);
  }

  // T=100: layer-2 final h (t=99) lands in parity-0 buffer.
  head_softmax<<<B_ / 4, 256, 0, stream>>>(hb[2][0], Wd, bd, out);
}